// Round 1
// 1972.941 us; speedup vs baseline: 1.4227x; 1.4227x over previous
//
#include <hip/hip_runtime.h>

#define BATCH   8192
#define DIMN    64
#define HIDN    128
#define N_STEPS 100
#define RT      32          // rows per block (8 per wave)
#define DT      0.01f
#define SQDT    0.1f

__device__ __forceinline__ float fast_tanh(float a) {
    // tanh(a) = 1 - 2/(exp(2a)+1); exact at +-inf saturation
    float e = __expf(2.0f * a);
    return 1.0f - 2.0f * __builtin_amdgcn_rcpf(e + 1.0f);
}

// wave-uniform broadcast: value of v on lane `lane` (VALU pipe, no LDS)
__device__ __forceinline__ float rl(float v, int lane) {
    return __int_as_float(__builtin_amdgcn_readlane(__float_as_int(v), lane));
}

__global__ __launch_bounds__(256, 1)
void sde_kernel(const float* __restrict__ x0,
                const float* __restrict__ noise,
                const float* __restrict__ Wd1, const float* __restrict__ bd1,
                const float* __restrict__ Wd2, const float* __restrict__ bd2,
                const float* __restrict__ Wg1, const float* __restrict__ bg1,
                const float* __restrict__ Wg2, const float* __restrict__ bg2,
                float* __restrict__ out)
{
    // LDS: weights only (131072 B). Activations live in registers.
    __shared__ float sW1d[DIMN * HIDN];   // [64][128] row-major
    __shared__ float sW1g[DIMN * HIDN];
    __shared__ float sW2d[HIDN * DIMN];   // [128][64] row-major
    __shared__ float sW2g[HIDN * DIMN];

    const int t = threadIdx.x;

    for (int i = t; i < DIMN * HIDN / 4; i += 256) {
        ((float4*)sW1d)[i] = ((const float4*)Wd1)[i];
        ((float4*)sW1g)[i] = ((const float4*)Wg1)[i];
        ((float4*)sW2d)[i] = ((const float4*)Wd2)[i];
        ((float4*)sW2g)[i] = ((const float4*)Wg2)[i];
    }

    const int w  = t >> 6;        // wave id 0..3
    const int l  = t & 63;        // lane
    const int ll = l & 31;
    const bool gate_half = (l >= 32);   // lanes 0..31: drift H, 32..63: gate H

    const long row0 = (long)blockIdx.x * RT + (long)w * 8;  // this wave's 8 rows

    // per-half L1 weights/bias; this lane owns cols {ll, ll+32, ll+64, ll+96}
    const float* w1p = gate_half ? sW1g : sW1d;
    const float* b1p = gate_half ? bg1  : bd1;

    float b1v[4];
    #pragma unroll
    for (int m = 0; m < 4; ++m) b1v[m] = b1p[ll + 32 * m];
    const float b2dv = bd2[l];
    const float b2gv = bg2[l];

    // persistent state: x[r] = x[row0+r][l]
    float x[8];
    #pragma unroll
    for (int r = 0; r < 8; ++r) {
        float v = x0[(row0 + r) * DIMN + l];
        x[r] = v;
        out[(row0 + r) * DIMN + l] = v;     // out[0] = x0
    }

    __syncthreads();   // weights staged; the ONLY barrier in the kernel

    float h[32];       // h[r*4+m] = H_half[r][ll + 32*m]

    for (int s = 0; s < N_STEPS; ++s) {
        // prefetch this step's noise (hidden under L1 compute)
        float nz[8];
        const float* np = noise + ((long)s * BATCH + row0) * DIMN + l;
        #pragma unroll
        for (int r = 0; r < 8; ++r) nz[r] = np[(long)r * DIMN];

        // ---------- L1: H = tanh(x @ W1 + b1), both MLPs via lane halves ----------
        #pragma unroll
        for (int i = 0; i < 32; ++i) h[i] = b1v[i & 3];

        #pragma unroll 4
        for (int k = 0; k < DIMN; ++k) {
            const float* wr = w1p + k * HIDN + ll;
            float w0 = wr[0], w1 = wr[32], w2 = wr[64], w3 = wr[96];
            #pragma unroll
            for (int r = 0; r < 8; ++r) {
                float xs = rl(x[r], k);     // x[row0+r][k], shared by both halves
                h[r*4+0] = fmaf(xs, w0, h[r*4+0]);
                h[r*4+1] = fmaf(xs, w1, h[r*4+1]);
                h[r*4+2] = fmaf(xs, w2, h[r*4+2]);
                h[r*4+3] = fmaf(xs, w3, h[r*4+3]);
            }
        }
        #pragma unroll
        for (int i = 0; i < 32; ++i) h[i] = fast_tanh(h[i]);

        // ---------- L2 drift: f[:, l] = Hd @ Wd2 + bd2 ----------
        float f[8], g[8];
        #pragma unroll
        for (int r = 0; r < 8; ++r) f[r] = b2dv;
        #pragma unroll
        for (int m = 0; m < 4; ++m) {
            #pragma unroll 4
            for (int kk = 0; kk < 32; ++kk) {
                float wv = sW2d[(m * 32 + kk) * DIMN + l];   // W2d[k][l], k=32m+kk
                #pragma unroll
                for (int r = 0; r < 8; ++r)
                    f[r] = fmaf(rl(h[r*4+m], kk), wv, f[r]); // Hd[r][32m+kk] from lane kk
            }
        }

        // ---------- L2 gate: g[:, l] = Hg @ Wg2 + bg2 ----------
        #pragma unroll
        for (int r = 0; r < 8; ++r) g[r] = b2gv;
        #pragma unroll
        for (int m = 0; m < 4; ++m) {
            #pragma unroll 4
            for (int kk = 0; kk < 32; ++kk) {
                float wv = sW2g[(m * 32 + kk) * DIMN + l];
                #pragma unroll
                for (int r = 0; r < 8; ++r)
                    g[r] = fmaf(rl(h[r*4+m], 32 + kk), wv, g[r]); // Hg from lane 32+kk
            }
        }

        // ---------- update + trajectory write ----------
        float* op = out + ((long)(s + 1) * BATCH + row0) * DIMN + l;
        #pragma unroll
        for (int r = 0; r < 8; ++r) {
            float xn = fmaf(f[r], DT, fmaf(g[r] * nz[r], SQDT, x[r]));
            x[r] = xn;
            op[(long)r * DIMN] = xn;
        }
    }
}

extern "C" void kernel_launch(void* const* d_in, const int* in_sizes, int n_in,
                              void* d_out, int out_size, void* d_ws, size_t ws_size,
                              hipStream_t stream) {
    const float* x0    = (const float*)d_in[0];
    // d_in[1] = t_span (unused; MLPs ignore t)
    const float* noise = (const float*)d_in[2];
    const float* Wd1   = (const float*)d_in[3];
    const float* bd1   = (const float*)d_in[4];
    const float* Wd2   = (const float*)d_in[5];
    const float* bd2   = (const float*)d_in[6];
    const float* Wg1   = (const float*)d_in[7];
    const float* bg1   = (const float*)d_in[8];
    const float* Wg2   = (const float*)d_in[9];
    const float* bg2   = (const float*)d_in[10];
    float* out = (float*)d_out;

    sde_kernel<<<BATCH / RT, 256, 0, stream>>>(
        x0, noise, Wd1, bd1, Wd2, bd2, Wg1, bg1, Wg2, bg2, out);
}

// Round 3
// 1763.357 us; speedup vs baseline: 1.5918x; 1.1189x over previous
//
#include <hip/hip_runtime.h>

#define BATCH   8192
#define DIMN    64
#define HIDN    128
#define N_STEPS 100
#define RT      32          // rows per block (4 per wave, 8 waves)
#define NTHR    512
#define DT      0.01f
#define SQDT    0.1f

__device__ __forceinline__ float fast_tanh(float a) {
    // tanh(a) = 1 - 2/(exp(2a)+1); exact at +-inf saturation
    float e = __expf(2.0f * a);
    return 1.0f - 2.0f * __builtin_amdgcn_rcpf(e + 1.0f);
}

// wave-uniform broadcast: value of v on lane `lane` (VALU pipe, no LDS)
__device__ __forceinline__ float rl(float v, int lane) {
    return __int_as_float(__builtin_amdgcn_readlane(__float_as_int(v), lane));
}

__global__ __launch_bounds__(NTHR, 1)
void sde_kernel(const float* __restrict__ x0,
                const float* __restrict__ noise,
                const float* __restrict__ Wd1, const float* __restrict__ bd1,
                const float* __restrict__ Wd2, const float* __restrict__ bd2,
                const float* __restrict__ Wg1, const float* __restrict__ bg1,
                const float* __restrict__ Wg2, const float* __restrict__ bg2,
                float* __restrict__ out)
{
    // Fragment-shaped weight tables. 131072 B total -> 1 block/CU, 8 waves.
    // sW1d4[k*32+c] = {W1d[k][c], W1d[k][c+32], W1d[k][c+64], W1d[k][c+96]}
    __shared__ float4 sW1d4[DIMN * 32];
    __shared__ float4 sW1g4[DIMN * 32];
    // sW2q[(k/2)*64+c] = {Wd2[k][c], Wg2[k][c], Wd2[k+1][c], Wg2[k+1][c]}
    __shared__ float4 sW2q[64 * DIMN];

    const int t = threadIdx.x;

    // ---- stage weights into fragment layout (once per block) ----
    for (int i = t; i < DIMN * 32; i += NTHR) {
        int k = i >> 5, c = i & 31;
        const float* wd = Wd1 + k * HIDN + c;
        const float* wg = Wg1 + k * HIDN + c;
        sW1d4[i] = make_float4(wd[0], wd[32], wd[64], wd[96]);
        sW1g4[i] = make_float4(wg[0], wg[32], wg[64], wg[96]);
    }
    for (int i = t; i < 64 * DIMN; i += NTHR) {
        int k2 = i >> 6, c = i & 63, k = 2 * k2;
        sW2q[i] = make_float4(Wd2[k * DIMN + c],       Wg2[k * DIMN + c],
                              Wd2[(k + 1) * DIMN + c], Wg2[(k + 1) * DIMN + c]);
    }

    const int w  = t >> 6;              // wave id 0..7
    const int l  = t & 63;              // lane
    const int ll = l & 31;
    const bool gate_half = (l >= 32);   // lanes 0..31: drift H, 32..63: gate H

    const long row0 = (long)blockIdx.x * RT + (long)w * 4;  // this wave's 4 rows

    // per-half L1 bias; this lane owns hidden cols {ll, ll+32, ll+64, ll+96}
    const float* b1p = gate_half ? bg1 : bd1;
    float b1v[4];
    #pragma unroll
    for (int m = 0; m < 4; ++m) b1v[m] = b1p[ll + 32 * m];
    const float b2dv = bd2[l];
    const float b2gv = bg2[l];

    // persistent state: x[r] = x[row0+r][l]
    float x[4];
    #pragma unroll
    for (int r = 0; r < 4; ++r) {
        float v = x0[(row0 + r) * DIMN + l];
        x[r] = v;
        out[(row0 + r) * DIMN + l] = v;     // out[0] = x0
    }

    __syncthreads();   // weights staged; the ONLY barrier in the kernel

    const float4* __restrict__ w1p = gate_half ? sW1g4 : sW1d4;
    const float* np = noise + row0 * DIMN + l;
    float* op = out + (BATCH + row0) * DIMN + l;

    float h[16];       // h[r*4+m] = H_half[row0+r][ll + 32*m]

    for (int s = 0; s < N_STEPS; ++s) {
        // prefetch this step's noise (hidden under L1 compute)
        float nz[4];
        #pragma unroll
        for (int r = 0; r < 4; ++r) nz[r] = np[(long)r * DIMN];
        np += (long)BATCH * DIMN;

        // ---------- L1: H = tanh(x @ W1 + b1), both MLPs via lane halves ----------
        #pragma unroll
        for (int i = 0; i < 16; ++i) h[i] = b1v[i & 3];

        #pragma unroll 2
        for (int k = 0; k < DIMN; k += 2) {
            float4 wa = w1p[k * 32 + ll];
            float4 wb = w1p[(k + 1) * 32 + ll];
            // batched broadcasts: 8 readlanes, THEN the FMAs (hazard-gap cover)
            float xs[8];
            #pragma unroll
            for (int r = 0; r < 4; ++r) { xs[r] = rl(x[r], k); xs[4 + r] = rl(x[r], k + 1); }
            #pragma unroll
            for (int r = 0; r < 4; ++r) {
                h[r*4+0] = fmaf(xs[r], wa.x, h[r*4+0]);
                h[r*4+1] = fmaf(xs[r], wa.y, h[r*4+1]);
                h[r*4+2] = fmaf(xs[r], wa.z, h[r*4+2]);
                h[r*4+3] = fmaf(xs[r], wa.w, h[r*4+3]);
            }
            #pragma unroll
            for (int r = 0; r < 4; ++r) {
                h[r*4+0] = fmaf(xs[4+r], wb.x, h[r*4+0]);
                h[r*4+1] = fmaf(xs[4+r], wb.y, h[r*4+1]);
                h[r*4+2] = fmaf(xs[4+r], wb.z, h[r*4+2]);
                h[r*4+3] = fmaf(xs[4+r], wb.w, h[r*4+3]);
            }
        }
        #pragma unroll
        for (int i = 0; i < 16; ++i) h[i] = fast_tanh(h[i]);

        // ---------- L2: f = Hd@Wd2+bd2, g = Hg@Wg2+bg2 (merged, shared b128) ----------
        float f[4], g[4];
        #pragma unroll
        for (int r = 0; r < 4; ++r) { f[r] = b2dv; g[r] = b2gv; }

        #pragma unroll
        for (int m = 0; m < 4; ++m) {
            #pragma unroll 2
            for (int k2 = 0; k2 < 16; ++k2) {
                float4 wq = sW2q[(m * 16 + k2) * DIMN + l];
                const int kk = 2 * k2;      // k within this m-block: 32m+kk
                // 16 batched broadcasts from both halves of the same reg
                float hd0[4], hg0[4], hd1[4], hg1[4];
                #pragma unroll
                for (int r = 0; r < 4; ++r) {
                    hd0[r] = rl(h[r*4+m], kk);
                    hg0[r] = rl(h[r*4+m], 32 + kk);
                    hd1[r] = rl(h[r*4+m], kk + 1);
                    hg1[r] = rl(h[r*4+m], 32 + kk + 1);
                }
                #pragma unroll
                for (int r = 0; r < 4; ++r) {
                    f[r] = fmaf(hd0[r], wq.x, f[r]);
                    g[r] = fmaf(hg0[r], wq.y, g[r]);
                    f[r] = fmaf(hd1[r], wq.z, f[r]);
                    g[r] = fmaf(hg1[r], wq.w, g[r]);
                }
            }
        }

        // ---------- x += f*dt + g*(dw*sqrt_dt); write traj ----------
        #pragma unroll
        for (int r = 0; r < 4; ++r) {
            float xn = fmaf(f[r], DT, fmaf(g[r] * nz[r], SQDT, x[r]));
            x[r] = xn;
            op[(long)r * DIMN] = xn;
        }
        op += (long)BATCH * DIMN;
    }
}

extern "C" void kernel_launch(void* const* d_in, const int* in_sizes, int n_in,
                              void* d_out, int out_size, void* d_ws, size_t ws_size,
                              hipStream_t stream) {
    const float* x0    = (const float*)d_in[0];
    // d_in[1] = t_span (unused; MLPs ignore t)
    const float* noise = (const float*)d_in[2];
    const float* Wd1   = (const float*)d_in[3];
    const float* bd1   = (const float*)d_in[4];
    const float* Wd2   = (const float*)d_in[5];
    const float* bd2   = (const float*)d_in[6];
    const float* Wg1   = (const float*)d_in[7];
    const float* bg1   = (const float*)d_in[8];
    const float* Wg2   = (const float*)d_in[9];
    const float* bg2   = (const float*)d_in[10];
    float* out = (float*)d_out;

    sde_kernel<<<BATCH / RT, NTHR, 0, stream>>>(
        x0, noise, Wd1, bd1, Wd2, bd2, Wg1, bg1, Wg2, bg2, out);
}

// Round 4
// 1347.384 us; speedup vs baseline: 2.0832x; 1.3087x over previous
//
#include <hip/hip_runtime.h>

#define BATCH   8192
#define DIMN    64
#define HIDN    128
#define N_STEPS 100
#define RT      32          // rows per block (4 per wave, 8 waves)
#define NTHR    512
#define DT      0.01f
#define SQDT    0.1f

#define ROR1    0x13C       // DPP ctrl: full-wave rotate-by-1 (lane l <- lane (l+1)&63 or inverse; see kb trick)

__device__ __forceinline__ float fast_tanh(float a) {
    // tanh(a) = 1 - 2/(exp(2a)+1); exact at +-inf saturation
    float e = __expf(2.0f * a);
    return 1.0f - 2.0f * __builtin_amdgcn_rcpf(e + 1.0f);
}

// full-wave rotate by one lane on the VALU pipe (no LDS, no readlane)
__device__ __forceinline__ int roti(int v) {
    return __builtin_amdgcn_update_dpp(0, v, ROR1, 0xF, 0xF, true);
}
__device__ __forceinline__ float rotf(float v) {
    return __int_as_float(roti(__float_as_int(v)));
}

__global__ __launch_bounds__(NTHR, 1)
void sde_kernel(const float* __restrict__ x0,
                const float* __restrict__ noise,
                const float* __restrict__ Wd1, const float* __restrict__ bd1,
                const float* __restrict__ Wd2, const float* __restrict__ bd2,
                const float* __restrict__ Wg1, const float* __restrict__ bg1,
                const float* __restrict__ Wg2, const float* __restrict__ bg2,
                float* __restrict__ out)
{
    // Systolic weight tables: 64 k-rows x 64 lane-cols x float4 = 64 KB each (131072 B total)
    // sW1[k*64+c] = {W1d[k][c], W1d[k][c+64], W1g[k][c], W1g[k][c+64]}
    // sW2[k*64+c] = {Wd2[k][c], Wd2[k+64][c], Wg2[k][c], Wg2[k+64][c]}
    __shared__ float4 sW1[64 * 64];
    __shared__ float4 sW2[64 * 64];

    const int t = threadIdx.x;

    for (int i = t; i < 64 * 64; i += NTHR) {
        const int k = i >> 6, c = i & 63;
        sW1[i] = make_float4(Wd1[k * HIDN + c], Wd1[k * HIDN + c + 64],
                             Wg1[k * HIDN + c], Wg1[k * HIDN + c + 64]);
        sW2[i] = make_float4(Wd2[k * DIMN + c], Wd2[(k + 64) * DIMN + c],
                             Wg2[k * DIMN + c], Wg2[(k + 64) * DIMN + c]);
    }

    const int w = t >> 6;               // wave 0..7
    const int l = t & 63;               // lane; owns x-col l and hidden cols {l, l+64} of both MLPs
    const long row0 = (long)blockIdx.x * RT + (long)w * 4;

    const float b1dA = bd1[l], b1dB = bd1[l + 64];
    const float b1gA = bg1[l], b1gB = bg1[l + 64];
    const float b2dv = bd2[l], b2gv = bg2[l];

    // persistent state: x[r] = x[row0+r][l]
    float x[4];
    #pragma unroll
    for (int r = 0; r < 4; ++r) {
        float v = x0[(row0 + r) * DIMN + l];
        x[r] = v;
        out[(row0 + r) * DIMN + l] = v;     // out[0] = x0
    }

    __syncthreads();   // weights staged; the ONLY barrier in the kernel

    const char* w1b = (const char*)sW1;
    const char* w2b = (const char*)sW2;
    const int l16 = l << 4;

    const float* np = noise + row0 * DIMN + l;
    float* op = out + (long)(BATCH + row0) * DIMN + l;

    for (int s = 0; s < N_STEPS; ++s) {
        // prefetch this step's noise (hidden under L1 compute)
        float nz[4];
        #pragma unroll
        for (int r = 0; r < 4; ++r) nz[r] = np[r * DIMN];
        np += (long)BATCH * DIMN;

        // ---------------- L1: H = tanh(x @ W1 + b1), systolic over k ----------------
        float hdA[4], hdB[4], hgA[4], hgB[4];
        #pragma unroll
        for (int r = 0; r < 4; ++r) { hdA[r] = b1dA; hdB[r] = b1dB; hgA[r] = b1gA; hgB[r] = b1gB; }

        // kb rotates WITH the data, so weight row always matches data provenance
        int kb = l << 10;
        float4 wv = *(const float4*)(w1b + kb + l16);
        kb = roti(kb);
        float4 wn = *(const float4*)(w1b + kb + l16);

        #pragma unroll 8
        for (int j = 0; j < 64; ++j) {
            kb = roti(kb);
            float4 wf = *(const float4*)(w1b + kb + l16);   // 2-ahead prefetch
            #pragma unroll
            for (int r = 0; r < 4; ++r) {
                hdA[r] = fmaf(x[r], wv.x, hdA[r]);
                hdB[r] = fmaf(x[r], wv.y, hdB[r]);
                hgA[r] = fmaf(x[r], wv.z, hgA[r]);
                hgB[r] = fmaf(x[r], wv.w, hgB[r]);
            }
            #pragma unroll
            for (int r = 0; r < 4; ++r) x[r] = rotf(x[r]);
            wv = wn; wn = wf;
        }
        // x is home again (64 rotations); kb is discarded & re-inited below

        #pragma unroll
        for (int r = 0; r < 4; ++r) {
            hdA[r] = fast_tanh(hdA[r]); hdB[r] = fast_tanh(hdB[r]);
            hgA[r] = fast_tanh(hgA[r]); hgB[r] = fast_tanh(hgB[r]);
        }

        // ---------------- L2: f = Hd@Wd2+bd2, g = Hg@Wg2+bg2, systolic over k ----------------
        float f[4], g[4];
        #pragma unroll
        for (int r = 0; r < 4; ++r) { f[r] = b2dv; g[r] = b2gv; }

        kb = l << 10;
        wv = *(const float4*)(w2b + kb + l16);
        kb = roti(kb);
        wn = *(const float4*)(w2b + kb + l16);

        #pragma unroll 8
        for (int j = 0; j < 64; ++j) {
            kb = roti(kb);
            float4 wf = *(const float4*)(w2b + kb + l16);   // 2-ahead prefetch
            #pragma unroll
            for (int r = 0; r < 4; ++r) {
                f[r] = fmaf(hdA[r], wv.x, f[r]);
                f[r] = fmaf(hdB[r], wv.y, f[r]);
                g[r] = fmaf(hgA[r], wv.z, g[r]);
                g[r] = fmaf(hgB[r], wv.w, g[r]);
            }
            #pragma unroll
            for (int r = 0; r < 4; ++r) {
                hdA[r] = rotf(hdA[r]); hdB[r] = rotf(hdB[r]);
                hgA[r] = rotf(hgA[r]); hgB[r] = rotf(hgB[r]);
            }
            wv = wn; wn = wf;
        }

        // ---------------- x += f*dt + g*(dw*sqrt_dt); write traj ----------------
        #pragma unroll
        for (int r = 0; r < 4; ++r) {
            float xn = fmaf(f[r], DT, fmaf(g[r] * nz[r], SQDT, x[r]));
            x[r] = xn;
            op[r * DIMN] = xn;
        }
        op += (long)BATCH * DIMN;
    }
}

extern "C" void kernel_launch(void* const* d_in, const int* in_sizes, int n_in,
                              void* d_out, int out_size, void* d_ws, size_t ws_size,
                              hipStream_t stream) {
    const float* x0    = (const float*)d_in[0];
    // d_in[1] = t_span (unused; MLPs ignore t)
    const float* noise = (const float*)d_in[2];
    const float* Wd1   = (const float*)d_in[3];
    const float* bd1   = (const float*)d_in[4];
    const float* Wd2   = (const float*)d_in[5];
    const float* bd2   = (const float*)d_in[6];
    const float* Wg1   = (const float*)d_in[7];
    const float* bg1   = (const float*)d_in[8];
    const float* Wg2   = (const float*)d_in[9];
    const float* bg2   = (const float*)d_in[10];
    float* out = (float*)d_out;

    sde_kernel<<<BATCH / RT, NTHR, 0, stream>>>(
        x0, noise, Wd1, bd1, Wd2, bd2, Wg1, bg1, Wg2, bg2, out);
}